// Round 3
// baseline (2061.873 us; speedup 1.0000x reference)
//
#include <hip/hip_runtime.h>
#include <cstdint>
#include <cstddef>

#define HIDDEN 7168
#define NEXP   256
#define KSTEPS (HIDDEN / 32)   // 224 total; 112 per K-half
#define BM     64
#define ROUTED_SCALE 2.5f

// Precision scheme (avoids f16 subnormals — weight scale 0.02 makes naive
// split residuals ~8e-6, below f16 min-normal 6.1e-5):
//   B pre-scaled by 2^6:  b' = 64*b;  bh = f16(b'), bl_s = f16((b'-bh)*4096)
//   A split in-kernel:    ah = f16(a), al_s = f16((a-ah)*4096)
//   acc_hh += ah*bh ; acc_c1 += al_s*bh + ah*bl_s   (consistent 2^12 scale)
//   logit = (acc_hh + acc_c1/4096) / 64

typedef _Float16 half8 __attribute__((ext_vector_type(8)));
typedef float    f32x4 __attribute__((ext_vector_type(4)));

// ---------------------------------------------------------------------------
// ws layout (fp16): for s in [0,224), part in {hi=0,lo=1}, nt in [0,16):
//   one 1KB chunk of 512 halves: [quad(4)][row(16)][j(8)]
//   element = split(64*W[nt*16+row][s*32 + quad*8 + j])
// Lane l of a wave reads its 16B B-fragment at chunk_base + l*16 —
// contiguous 1KB per fragment load, perfectly coalesced.
// ---------------------------------------------------------------------------
__global__ void convert_w(const float* __restrict__ w, _Float16* __restrict__ ws) {
    int e = blockIdx.x;            // expert 0..255
    int nt = e >> 4, row = e & 15;
    for (int k = threadIdx.x; k < HIDDEN; k += 256) {
        float x = w[(size_t)e * HIDDEN + k] * 64.0f;
        _Float16 hi = (_Float16)x;
        _Float16 lo = (_Float16)((x - (float)hi) * 4096.0f);
        int s = k >> 5, q = (k >> 3) & 3, j = k & 7;
        size_t off = (size_t)(q * 16 + row) * 8 + j;
        ws[((size_t)((s * 2 + 0) * 16 + nt) << 9) + off] = hi;
        ws[((size_t)((s * 2 + 1) * 16 + nt) << 9) + off] = lo;
    }
}

// ---------------------------------------------------------------------------
// Fused gate kernel: 256 blocks x 1024 threads (16 waves).
// Block = 64 tokens x 256 experts, split-K x2 inside the block:
//   wave = (kh, wm, wn): K-half kh, rows [wm*32, wm*32+32), experts
//   [wn*64, wn*64+64). 16 waves/CU = 4 waves/SIMD (round-1 had only 2),
//   with round-1's per-wave intensity (24 MFMA : 12 loads per k-step) and
//   round-1's B traffic (1.88 GB total; round-2's 3.76 GB regressed).
// Epilogue: kh=0 writes logits to LDS, barrier, kh=1 accumulates.
// ---------------------------------------------------------------------------
__global__ __launch_bounds__(1024, 4) void gate_kernel(
    const float* __restrict__ hidden,
    const _Float16* __restrict__ wsB,
    const float* __restrict__ bias,
    float* __restrict__ out) {

    __shared__ float lds[BM * 256];   // 64 KiB

    const int tid    = threadIdx.x;
    const int w      = tid >> 6;      // 0..15
    const int kh     = w >> 3;        // 0..1  K-half
    const int ws8    = w & 7;
    const int wm     = ws8 >> 2;      // 0..1 token half (32 rows each)
    const int wn     = ws8 & 3;       // 0..3 expert quarter
    const int l      = tid & 63;
    const int lane15 = l & 15;
    const int quad   = l >> 4;
    const size_t blockRow = (size_t)blockIdx.x * BM;
    const int sbase = kh * (KSTEPS / 2);   // 0 or 112

    const float* A0 = hidden + (blockRow + wm * 32) * HIDDEN + quad * 8;
    const float* Ap[2];
#pragma unroll
    for (int mt = 0; mt < 2; ++mt)
        Ap[mt] = A0 + (size_t)(mt * 16 + lane15) * HIDDEN;

    const _Float16* Bl = wsB + l * 8;   // lane's 16B slot within each chunk

    f32x4 acc_hh[2][4], acc_c1[2][4];
#pragma unroll
    for (int i = 0; i < 2; ++i)
#pragma unroll
        for (int j = 0; j < 4; ++j) {
            acc_hh[i][j] = (f32x4)0.0f;
            acc_c1[i][j] = (f32x4)0.0f;
        }

    auto loadA = [&](int s, f32x4 (&a)[2][2]) {
#pragma unroll
        for (int mt = 0; mt < 2; ++mt) {
            const float* p = Ap[mt] + s * 32;
            a[mt][0] = *(const f32x4*)(p);
            a[mt][1] = *(const f32x4*)(p + 4);
        }
    };
    auto loadB = [&](int s, half8 (&bh)[4], half8 (&bl)[4]) {
#pragma unroll
        for (int jj = 0; jj < 4; ++jj) {
            int nt = wn * 4 + jj;
            bh[jj] = *(const half8*)(Bl + ((size_t)((s * 2 + 0) * 16 + nt) << 9));
            bl[jj] = *(const half8*)(Bl + ((size_t)((s * 2 + 1) * 16 + nt) << 9));
        }
    };
    auto compute = [&](f32x4 (&a)[2][2], half8 (&bh)[4], half8 (&bl)[4]) {
        half8 ah[2], al[2];
#pragma unroll
        for (int mt = 0; mt < 2; ++mt) {
#pragma unroll
            for (int e = 0; e < 8; ++e) {
                float x = (e < 4) ? a[mt][0][e] : a[mt][1][e - 4];
                _Float16 h = (_Float16)x;
                ah[mt][e] = h;
                al[mt][e] = (_Float16)((x - (float)h) * 4096.0f);
            }
        }
        // product loops outermost: 8 independent MFMAs between same-acc deps
#pragma unroll
        for (int jj = 0; jj < 4; ++jj)
#pragma unroll
            for (int mt = 0; mt < 2; ++mt)
                acc_hh[mt][jj] = __builtin_amdgcn_mfma_f32_16x16x32_f16(ah[mt], bh[jj], acc_hh[mt][jj], 0, 0, 0);
#pragma unroll
        for (int jj = 0; jj < 4; ++jj)
#pragma unroll
            for (int mt = 0; mt < 2; ++mt)
                acc_c1[mt][jj] = __builtin_amdgcn_mfma_f32_16x16x32_f16(al[mt], bh[jj], acc_c1[mt][jj], 0, 0, 0);
#pragma unroll
        for (int jj = 0; jj < 4; ++jj)
#pragma unroll
            for (int mt = 0; mt < 2; ++mt)
                acc_c1[mt][jj] = __builtin_amdgcn_mfma_f32_16x16x32_f16(ah[mt], bl[jj], acc_c1[mt][jj], 0, 0, 0);
    };

    // software pipeline, unroll x2 ping-pong (no dynamic register indexing)
    f32x4 a0[2][2], a1[2][2];
    half8 bh0[4], bl0[4], bh1[4], bl1[4];

    loadA(sbase, a0); loadB(sbase, bh0, bl0);
    for (int i = 0; i < KSTEPS / 2; i += 2) {
        int s = sbase + i;
        loadA(s + 1, a1); loadB(s + 1, bh1, bl1);   // i+1 <= 111 always valid
        compute(a0, bh0, bl0);
        if (i != KSTEPS / 2 - 2) { loadA(s + 2, a0); loadB(s + 2, bh0, bl0); }
        compute(a1, bh1, bl1);
    }

    // ---------------- epilogue: logits -> LDS (two-phase K-half sum) -------
    if (kh == 0) {
#pragma unroll
        for (int mt = 0; mt < 2; ++mt)
#pragma unroll
            for (int jj = 0; jj < 4; ++jj)
#pragma unroll
                for (int r = 0; r < 4; ++r) {
                    int row = wm * 32 + mt * 16 + quad * 4 + r;
                    int col = wn * 64 + jj * 16 + lane15;
                    lds[row * 256 + col] =
                        acc_hh[mt][jj][r] + acc_c1[mt][jj][r] * (1.0f / 4096.0f);
                }
    }
    __syncthreads();
    if (kh == 1) {
#pragma unroll
        for (int mt = 0; mt < 2; ++mt)
#pragma unroll
            for (int jj = 0; jj < 4; ++jj)
#pragma unroll
                for (int r = 0; r < 4; ++r) {
                    int row = wm * 32 + mt * 16 + quad * 4 + r;
                    int col = wn * 64 + jj * 16 + lane15;
                    float v = lds[row * 256 + col] +
                        (acc_hh[mt][jj][r] + acc_c1[mt][jj][r] * (1.0f / 4096.0f));
                    lds[row * 256 + col] = v * (1.0f / 64.0f);
                }
    }
    __syncthreads();

    // ---------------- gating: threads 0..511, 8 lanes per token ------------
    if (tid < 512) {
        const int t = tid >> 3;   // token 0..63
        const int p = tid & 7;    // group p, experts [p*32, p*32+32)
        float* Lrow = &lds[t * 256];
        const int rot = (t * 4 + p) & 31;   // bank de-conflict rotation

        // pass 1: sigmoid (stored back), biased score, per-group top-2
        float t0 = -1e30f, t1 = -1e30f;
        for (int i = 0; i < 32; ++i) {
            int col = p * 32 + ((i + rot) & 31);
            float x  = Lrow[col];
            float sg = 1.0f / (1.0f + expf(-x));
            Lrow[col] = sg;
            float swb = sg + bias[col];
            t1 = fmaxf(t1, fminf(t0, swb));
            t0 = fmaxf(t0, swb);
        }
        float gs = t0 + t1;   // this lane's group score

        // rank my group among the 8 (lower index wins ties, matching lax.top_k)
        int rank = 0;
#pragma unroll
        for (int m = 1; m < 8; ++m) {
            float ov = __shfl_xor(gs, m);
            int   og = p ^ m;
            rank += (int)((ov > gs) || (ov == gs && og < p));
        }
        bool sel = rank < 4;

        // pass 2: per-lane top-8 (value=swb, carry raw sigmoid + col)
        float lv[8], lsr[8]; int li[8];
#pragma unroll
        for (int k = 0; k < 8; ++k) { lv[k] = -1.0f; lsr[k] = 0.0f; li[k] = 1 << 30; }
        for (int i = 0; i < 32; ++i) {
            int col = p * 32 + ((i + rot) & 31);
            float sg  = Lrow[col];
            float swb = sg + bias[col];
            float v = (sel && swb > 0.0f) ? swb : -1.0f;
            if (v > lv[7]) {
                float cv = v, cs = sg; int ci = col;
#pragma unroll
                for (int k = 0; k < 8; ++k) {
                    bool sw = cv > lv[k];
                    float tv = lv[k], ts = lsr[k]; int ti = li[k];
                    lv[k]  = sw ? cv : tv;  lsr[k] = sw ? cs : ts;  li[k] = sw ? ci : ti;
                    cv = sw ? tv : cv;  cs = sw ? ts : cs;  ci = sw ? ti : ci;
                }
            }
        }

        // merge 8 lanes' lists: 8 rounds of butterfly-max, pop owner
        unsigned selmask = 0u;
        float denom = 0.0f;
#pragma unroll
        for (int round = 0; round < 8; ++round) {
            float hv = lv[0], hs = lsr[0]; int hidx = li[0];
#pragma unroll
            for (int m = 1; m <= 4; m <<= 1) {
                float ov = __shfl_xor(hv, m);
                float os = __shfl_xor(hs, m);
                int   oi = __shfl_xor(hidx, m);
                bool take = (ov > hv) || (ov == hv && oi < hidx);
                hv = take ? ov : hv;  hs = take ? os : hs;  hidx = take ? oi : hidx;
            }
            if (hv > 0.0f) {
                denom += hs;
                if ((hidx >> 5) == p) selmask |= (1u << (hidx & 31));
            }
            if (li[0] == hidx) {   // cols are unique across lanes -> unique owner
#pragma unroll
                for (int k = 0; k < 7; ++k) { lv[k] = lv[k + 1]; lsr[k] = lsr[k + 1]; li[k] = li[k + 1]; }
                lv[7] = -1.0f; lsr[7] = 0.0f; li[7] = 1 << 30;
            }
        }

        // pass 3: write output row (all 256 per token; zeros elsewhere)
        float inv = ROUTED_SCALE / (denom + 1e-20f);
        float* orow = out + (blockRow + (size_t)t) * NEXP;
        for (int i = 0; i < 32; i += 4) {
            int ii = (i + ((rot & 7) << 2)) & 31;   // bank-rotated start
            int col = p * 32 + ii;
            f32x4 v;
#pragma unroll
            for (int u = 0; u < 4; ++u) {
                float sg = Lrow[col + u];
                bool on = (selmask >> ((col + u) & 31)) & 1u;
                v[u] = on ? sg * inv : 0.0f;
            }
            *(f32x4*)(orow + col) = v;
        }
    }
}

extern "C" void kernel_launch(void* const* d_in, const int* in_sizes, int n_in,
                              void* d_out, int out_size, void* d_ws, size_t ws_size,
                              hipStream_t stream) {
    const float* hidden = (const float*)d_in[0];
    const float* weight = (const float*)d_in[1];
    const float* bias   = (const float*)d_in[2];
    float* out = (float*)d_out;
    _Float16* ws = (_Float16*)d_ws;   // needs 2*256*7168*2 = 7,340,032 bytes

    convert_w<<<NEXP, 256, 0, stream>>>(weight, ws);
    gate_kernel<<<16384 / BM, 1024, 0, stream>>>(hidden, ws, bias, out);
}

// Round 4
// 939.184 us; speedup vs baseline: 2.1954x; 2.1954x over previous
//
#include <hip/hip_runtime.h>
#include <cstdint>
#include <cstddef>

#define HIDDEN 7168
#define NEXP   256
#define KSTEPS 224          // HIDDEN / 32
#define KHALF  112          // per split-K half
#define BM     128
#define ROUTED_SCALE 2.5f

// Precision scheme (avoids f16 subnormals — weight scale 0.02 makes naive
// split residuals ~8e-6, below f16 min-normal 6.1e-5):
//   B pre-scaled by 2^6:  b' = 64*b;  bh = f16(b'), bl_s = f16((b'-bh)*4096)
//   A split in-kernel:    ah = f16(a), al_s = f16((a-ah)*4096)
//   acc_hh += ah*bh ; acc_c1 += al_s*bh + ah*bl_s   (consistent 2^12 scale)
//   logit = (acc_hh + acc_c1/4096) / 64   (the /64 is applied in gate_finish)

typedef _Float16 half8 __attribute__((ext_vector_type(8)));
typedef float    f32x4 __attribute__((ext_vector_type(4)));

// ---------------------------------------------------------------------------
// ws layout (fp16): for s in [0,224), part in {hi=0,lo=1}, nt in [0,16):
//   one 1KB chunk of 512 halves: [quad(4)][row(16)][j(8)]
//   element = split(64*W[nt*16+row][s*32 + quad*8 + j])
// Lane l of a wave reads its 16B B-fragment at chunk_base + l*16 —
// contiguous 1KB per fragment load, perfectly coalesced.
// ---------------------------------------------------------------------------
__global__ void convert_w(const float* __restrict__ w, _Float16* __restrict__ ws) {
    int e = blockIdx.x;            // expert 0..255
    int nt = e >> 4, row = e & 15;
    for (int k = threadIdx.x; k < HIDDEN; k += 256) {
        float x = w[(size_t)e * HIDDEN + k] * 64.0f;
        _Float16 hi = (_Float16)x;
        _Float16 lo = (_Float16)((x - (float)hi) * 4096.0f);
        int s = k >> 5, q = (k >> 3) & 3, j = k & 7;
        size_t off = (size_t)(q * 16 + row) * 8 + j;
        ws[((size_t)((s * 2 + 0) * 16 + nt) << 9) + off] = hi;
        ws[((size_t)((s * 2 + 1) * 16 + nt) << 9) + off] = lo;
    }
}

// ---------------------------------------------------------------------------
// GEMM partial kernel: 512 blocks x 512 threads (8 waves = 4wm x 2wn).
// Block = 128 tokens x 128 experts x half-K. Wave tile = 32 rows x 64 experts
// = R1's proven shape (24 MFMA : 12 loads per k-step, 92 VGPR).
// 2 blocks/CU -> 4 waves/SIMD. bid decode pins one (nh,kh) combo per XCD
// (consecutive bids round-robin XCDs) so each XCD's 1.75 MB B-quarter is
// L2-resident. K-halves combine via atomicAdd into zeroed `out`.
// ---------------------------------------------------------------------------
__global__ __launch_bounds__(512, 2) void gemm_kernel(
    const float* __restrict__ hidden,
    const _Float16* __restrict__ wsB,
    float* __restrict__ out) {

    const int bid  = blockIdx.x;            // 0..511
    const int nhkh = (bid >> 1) & 3;        // constant per XCD (bid%8 round-robin)
    const int nh   = nhkh >> 1;             // expert half
    const int kh   = nhkh & 1;              // K half
    const int m    = ((bid >> 3) << 1) | (bid & 1);   // 0..127, bijective

    const int tid    = threadIdx.x;
    const int w      = tid >> 6;      // 0..7
    const int wm     = w >> 1;        // 0..3 token quarter (32 rows)
    const int wn     = w & 1;         // 0..1 expert half-of-half (64 experts)
    const int l      = tid & 63;
    const int lane15 = l & 15;
    const int quad   = l >> 4;
    const size_t blockRow = (size_t)m * BM;
    const int sbase = kh * KHALF;     // 0 or 112

    const float* A0 = hidden + (blockRow + wm * 32) * HIDDEN + quad * 8;
    const float* Ap[2];
#pragma unroll
    for (int mt = 0; mt < 2; ++mt)
        Ap[mt] = A0 + (size_t)(mt * 16 + lane15) * HIDDEN;

    const _Float16* Bl = wsB + l * 8;   // lane's 16B slot within each chunk

    f32x4 acc_hh[2][4], acc_c1[2][4];
#pragma unroll
    for (int i = 0; i < 2; ++i)
#pragma unroll
        for (int j = 0; j < 4; ++j) {
            acc_hh[i][j] = (f32x4)0.0f;
            acc_c1[i][j] = (f32x4)0.0f;
        }

    auto loadA = [&](int s, f32x4 (&a)[2][2]) {
#pragma unroll
        for (int mt = 0; mt < 2; ++mt) {
            const float* p = Ap[mt] + s * 32;
            a[mt][0] = *(const f32x4*)(p);
            a[mt][1] = *(const f32x4*)(p + 4);
        }
    };
    auto loadB = [&](int s, half8 (&bh)[4], half8 (&bl)[4]) {
#pragma unroll
        for (int jj = 0; jj < 4; ++jj) {
            int nt = nh * 8 + wn * 4 + jj;
            bh[jj] = *(const half8*)(Bl + ((size_t)((s * 2 + 0) * 16 + nt) << 9));
            bl[jj] = *(const half8*)(Bl + ((size_t)((s * 2 + 1) * 16 + nt) << 9));
        }
    };
    auto compute = [&](f32x4 (&a)[2][2], half8 (&bh)[4], half8 (&bl)[4]) {
        half8 ah[2], al[2];
#pragma unroll
        for (int mt = 0; mt < 2; ++mt) {
#pragma unroll
            for (int e = 0; e < 8; ++e) {
                float x = (e < 4) ? a[mt][0][e] : a[mt][1][e - 4];
                _Float16 h = (_Float16)x;
                ah[mt][e] = h;
                al[mt][e] = (_Float16)((x - (float)h) * 4096.0f);
            }
        }
        // product loops outermost: 8 independent MFMAs between same-acc deps
#pragma unroll
        for (int jj = 0; jj < 4; ++jj)
#pragma unroll
            for (int mt = 0; mt < 2; ++mt)
                acc_hh[mt][jj] = __builtin_amdgcn_mfma_f32_16x16x32_f16(ah[mt], bh[jj], acc_hh[mt][jj], 0, 0, 0);
#pragma unroll
        for (int jj = 0; jj < 4; ++jj)
#pragma unroll
            for (int mt = 0; mt < 2; ++mt)
                acc_c1[mt][jj] = __builtin_amdgcn_mfma_f32_16x16x32_f16(al[mt], bh[jj], acc_c1[mt][jj], 0, 0, 0);
#pragma unroll
        for (int jj = 0; jj < 4; ++jj)
#pragma unroll
            for (int mt = 0; mt < 2; ++mt)
                acc_c1[mt][jj] = __builtin_amdgcn_mfma_f32_16x16x32_f16(ah[mt], bl[jj], acc_c1[mt][jj], 0, 0, 0);
    };

    // software pipeline, unroll x2 ping-pong (no dynamic register indexing)
    f32x4 a0[2][2], a1[2][2];
    half8 bh0[4], bl0[4], bh1[4], bl1[4];

    loadA(sbase, a0); loadB(sbase, bh0, bl0);
    for (int i = 0; i < KHALF; i += 2) {
        int s = sbase + i;
        loadA(s + 1, a1); loadB(s + 1, bh1, bl1);   // i+1 <= 111 always valid
        compute(a0, bh0, bl0);
        if (i != KHALF - 2) { loadA(s + 2, a0); loadB(s + 2, bh0, bl0); }
        compute(a1, bh1, bl1);
    }

    // ---------------- epilogue: atomic-accumulate partial logits -----------
#pragma unroll
    for (int mt = 0; mt < 2; ++mt)
#pragma unroll
        for (int jj = 0; jj < 4; ++jj)
#pragma unroll
            for (int r = 0; r < 4; ++r) {
                size_t row = blockRow + wm * 32 + mt * 16 + quad * 4 + r;
                int col = nh * 128 + wn * 64 + jj * 16 + lane15;
                float v = acc_hh[mt][jj][r] + acc_c1[mt][jj][r] * (1.0f / 4096.0f);
                atomicAdd(&out[row * NEXP + col], v);   // 2 contributors: deterministic
            }
}

// ---------------------------------------------------------------------------
// Gating finish: 512 blocks x 256 threads; 32 tokens/block, 8 lanes/token.
// Reads raw logits from `out` (scaled by 1/64 on stage-in), gates, writes
// the final row back in place.
// ---------------------------------------------------------------------------
__global__ __launch_bounds__(256, 4) void gate_finish(
    const float* __restrict__ bias,
    float* __restrict__ out) {

    __shared__ float lds[32 * 256];   // 32 KiB

    const int tid = threadIdx.x;
    const size_t tbase = (size_t)blockIdx.x * 32;

    // stage 32 rows into LDS with the 1/64 logit scale applied
#pragma unroll
    for (int i = 0; i < 8; ++i) {
        int idx = tid + i * 256;       // 0..2047
        int row = idx >> 6, c4 = idx & 63;
        f32x4 v = *(const f32x4*)(out + (tbase + row) * NEXP + c4 * 4);
        v = v * (1.0f / 64.0f);
        *(f32x4*)(&lds[row * 256 + c4 * 4]) = v;
    }
    __syncthreads();

    const int t = tid >> 3;   // token 0..31
    const int p = tid & 7;    // group p, experts [p*32, p*32+32)
    float* Lrow = &lds[t * 256];
    const int rot = (t * 4 + p) & 31;   // bank de-conflict rotation (2-way max)

    // pass 1: sigmoid (stored back), biased score, per-group top-2
    float t0 = -1e30f, t1 = -1e30f;
    for (int i = 0; i < 32; ++i) {
        int col = p * 32 + ((i + rot) & 31);
        float x  = Lrow[col];
        float sg = 1.0f / (1.0f + expf(-x));
        Lrow[col] = sg;
        float swb = sg + bias[col];
        t1 = fmaxf(t1, fminf(t0, swb));
        t0 = fmaxf(t0, swb);
    }
    float gs = t0 + t1;   // this lane's group score

    // rank my group among the 8 (lower index wins ties, matching lax.top_k)
    int rank = 0;
#pragma unroll
    for (int m = 1; m < 8; ++m) {
        float ov = __shfl_xor(gs, m);
        int   og = p ^ m;
        rank += (int)((ov > gs) || (ov == gs && og < p));
    }
    bool sel = rank < 4;

    // pass 2: per-lane top-8 (value=swb, carry raw sigmoid + col)
    float lv[8], lsr[8]; int li[8];
#pragma unroll
    for (int k = 0; k < 8; ++k) { lv[k] = -1.0f; lsr[k] = 0.0f; li[k] = 1 << 30; }
    for (int i = 0; i < 32; ++i) {
        int col = p * 32 + ((i + rot) & 31);
        float sg  = Lrow[col];
        float swb = sg + bias[col];
        float v = (sel && swb > 0.0f) ? swb : -1.0f;
        if (v > lv[7]) {
            float cv = v, cs = sg; int ci = col;
#pragma unroll
            for (int k = 0; k < 8; ++k) {
                bool sw = cv > lv[k];
                float tv = lv[k], ts = lsr[k]; int ti = li[k];
                lv[k]  = sw ? cv : tv;  lsr[k] = sw ? cs : ts;  li[k] = sw ? ci : ti;
                cv = sw ? tv : cv;  cs = sw ? ts : cs;  ci = sw ? ti : ci;
            }
        }
    }

    // merge 8 lanes' lists: 8 rounds of butterfly-max, pop owner
    unsigned selmask = 0u;
    float denom = 0.0f;
#pragma unroll
    for (int round = 0; round < 8; ++round) {
        float hv = lv[0], hs = lsr[0]; int hidx = li[0];
#pragma unroll
        for (int m = 1; m <= 4; m <<= 1) {
            float ov = __shfl_xor(hv, m);
            float os = __shfl_xor(hs, m);
            int   oi = __shfl_xor(hidx, m);
            bool take = (ov > hv) || (ov == hv && oi < hidx);
            hv = take ? ov : hv;  hs = take ? os : hs;  hidx = take ? oi : hidx;
        }
        if (hv > 0.0f) {
            denom += hs;
            if ((hidx >> 5) == p) selmask |= (1u << (hidx & 31));
        }
        if (li[0] == hidx) {   // cols are unique across lanes -> unique owner
#pragma unroll
            for (int k = 0; k < 7; ++k) { lv[k] = lv[k + 1]; lsr[k] = lsr[k + 1]; li[k] = li[k + 1]; }
            lv[7] = -1.0f; lsr[7] = 0.0f; li[7] = 1 << 30;
        }
    }

    // pass 3: write output row (all 256 per token; zeros elsewhere)
    float inv = ROUTED_SCALE / (denom + 1e-20f);
    float* orow = out + (tbase + (size_t)t) * NEXP;
    for (int i = 0; i < 32; i += 4) {
        int ii = (i + ((rot & 7) << 2)) & 31;   // bank-rotated start
        int col = p * 32 + ii;
        f32x4 v;
#pragma unroll
        for (int u = 0; u < 4; ++u) {
            float sg = Lrow[col + u];
            bool on = (selmask >> ((col + u) & 31)) & 1u;
            v[u] = on ? sg * inv : 0.0f;
        }
        *(f32x4*)(orow + col) = v;
    }
}

extern "C" void kernel_launch(void* const* d_in, const int* in_sizes, int n_in,
                              void* d_out, int out_size, void* d_ws, size_t ws_size,
                              hipStream_t stream) {
    const float* hidden = (const float*)d_in[0];
    const float* weight = (const float*)d_in[1];
    const float* bias   = (const float*)d_in[2];
    float* out = (float*)d_out;
    _Float16* ws = (_Float16*)d_ws;   // needs 2*256*7168*2 = 7,340,032 bytes

    convert_w<<<NEXP, 256, 0, stream>>>(weight, ws);
    hipMemsetAsync(out, 0, (size_t)16384 * NEXP * sizeof(float), stream);
    gemm_kernel<<<512, 512, 0, stream>>>(hidden, ws, out);
    gate_finish<<<512, 256, 0, stream>>>(bias, out);
}

// Round 5
// 841.795 us; speedup vs baseline: 2.4494x; 1.1157x over previous
//
#include <hip/hip_runtime.h>
#include <cstdint>
#include <cstddef>

#define HIDDEN 7168
#define NEXP   256
#define KSTEPS 224
#define BM     64
#define ROUTED_SCALE 2.5f

// Precision scheme (avoids f16 subnormals):
//   B pre-scaled by 2^6:  b' = 64*b;  bh = f16(b'), bl_s = f16((b'-bh)*4096)
//   A split at LDS-stage time: ah = f16(a), al_s = f16((a-ah)*4096)
//   acc_hh += ah*bh ; acc_c1 += al_s*bh + ah*bl_s   (consistent 2^12 scale)
//   logit = (acc_hh + acc_c1/4096) / 64

typedef _Float16 half8 __attribute__((ext_vector_type(8)));
typedef float    f32x4 __attribute__((ext_vector_type(4)));

// ---------------------------------------------------------------------------
// ws layout (fp16): for s in [0,224), part in {hi=0,lo=1}, nt in [0,16):
//   one 1KB chunk of 512 halves: [quad(4)][row(16)][j(8)]
//   element = split(64*W[nt*16+row][s*32 + quad*8 + j])
// Lane l of a wave reads its 16B B-fragment at chunk_base + l*16.
// ---------------------------------------------------------------------------
__global__ void convert_w(const float* __restrict__ w, _Float16* __restrict__ ws) {
    int e = blockIdx.x;            // expert 0..255
    int nt = e >> 4, row = e & 15;
    for (int k = threadIdx.x; k < HIDDEN; k += 256) {
        float x = w[(size_t)e * HIDDEN + k] * 64.0f;
        _Float16 hi = (_Float16)x;
        _Float16 lo = (_Float16)((x - (float)hi) * 4096.0f);
        int s = k >> 5, q = (k >> 3) & 3, j = k & 7;
        size_t off = (size_t)(q * 16 + row) * 8 + j;
        ws[((size_t)((s * 2 + 0) * 16 + nt) << 9) + off] = hi;
        ws[((size_t)((s * 2 + 1) * 16 + nt) << 9) + off] = lo;
    }
}

// ---------------------------------------------------------------------------
// Fused gate kernel: 256 blocks x 256 threads (4 waves of 64x64 tiles).
// Request-rate design (R1/R4 showed ~1 cache-line req/cyc/CU is the wall):
//   B direct from L2, each chunk read ONCE per block: 512 req/kstep.
//   A staged to LDS coalesced + pre-split to f16 hi/lo planes: 128 req/kstep.
//   => ~640 req/kstep vs R1's 2048.  LDS: A-staging 32KB (2x16KB chunks of
//   2 ksteps), logits 64KB overlay after GEMM.  64KB block -> 2 blocks/CU.
// ---------------------------------------------------------------------------
__global__ __launch_bounds__(256, 2) void gate_kernel(
    const float* __restrict__ hidden,
    const _Float16* __restrict__ wsB,
    const float* __restrict__ bias,
    float* __restrict__ out) {

    __shared__ char smem[65536];
    float* L = (float*)smem;          // logits overlay (epilogue only)

    const int tid    = threadIdx.x;
    const int w      = tid >> 6;      // wave 0..3: experts [w*64, w*64+64)
    const int l      = tid & 63;
    const int lane15 = l & 15;
    const int quad   = l >> 4;
    const size_t blockRow = (size_t)blockIdx.x * BM;

    // ---------------- A staging: thread covers (row0, row0+32) x grp -------
    // 2-kstep chunk = 64 rows x 64 floats; grp = 8-float group (0..7).
    // LDS layout: 16 planes of 1KB: plane pi = mt*4 + e*2 + part;
    //   byte in plane = ((row&15)*4 + quad)*16  (per-lane-ordered, conflict-free)
    const int grp  = tid & 7;
    const int e_s  = grp >> 2;        // kstep parity staged by this thread
    const int q_s  = grp & 3;         // quad within kstep
    const int row0 = tid >> 3;        // 0..31 (also stages row0+32)
    const float* Ag = hidden + blockRow * HIDDEN + grp * 8;

    f32x4 sA[4];                      // staged raw A (2 rows x 8 floats)

    auto stage_load = [&](int sp) {
        const float* p0 = Ag + (size_t)row0 * HIDDEN + sp * 32;
        const float* p1 = Ag + (size_t)(row0 + 32) * HIDDEN + sp * 32;
        sA[0] = *(const f32x4*)(p0);
        sA[1] = *(const f32x4*)(p0 + 4);
        sA[2] = *(const f32x4*)(p1);
        sA[3] = *(const f32x4*)(p1 + 4);
    };
    auto stage_write = [&](int buf) {
        char* Ab = smem + buf * 16384;
#pragma unroll
        for (int i = 0; i < 2; ++i) {
            int row = row0 + i * 32;
            half8 hh, hl;
#pragma unroll
            for (int u = 0; u < 8; ++u) {
                float x = (u < 4) ? sA[i * 2][u] : sA[i * 2 + 1][u - 4];
                _Float16 h = (_Float16)x;
                hh[u] = h;
                hl[u] = (_Float16)((x - (float)h) * 4096.0f);
            }
            int pi   = (row >> 4) * 4 + e_s * 2;
            int slot = ((row & 15) * 4 + q_s) << 4;
            *(half8*)(Ab + (pi << 10) + slot)       = hh;
            *(half8*)(Ab + ((pi + 1) << 10) + slot) = hl;
        }
    };

    // ---------------- B: direct global loads (proven R1 path) --------------
    const _Float16* Bl = wsB + l * 8;
    auto loadB = [&](int s, half8 (&bh)[4], half8 (&bl)[4]) {
#pragma unroll
        for (int jj = 0; jj < 4; ++jj) {
            int nt = w * 4 + jj;
            bh[jj] = *(const half8*)(Bl + ((size_t)((s * 2 + 0) * 16 + nt) << 9));
            bl[jj] = *(const half8*)(Bl + ((size_t)((s * 2 + 1) * 16 + nt) << 9));
        }
    };

    f32x4 acc_hh[4][4], acc_c1[4][4];
#pragma unroll
    for (int i = 0; i < 4; ++i)
#pragma unroll
        for (int j = 0; j < 4; ++j) {
            acc_hh[i][j] = (f32x4)0.0f;
            acc_c1[i][j] = (f32x4)0.0f;
        }

    auto computeK = [&](int buf, int e, half8 (&bh)[4], half8 (&bl)[4]) {
        char* Ab = smem + buf * 16384;
        const int slot = (lane15 * 4 + quad) << 4;
#pragma unroll
        for (int mt = 0; mt < 4; ++mt) {
            int pi = mt * 4 + e * 2;
            half8 ah = *(const half8*)(Ab + (pi << 10) + slot);
            half8 al = *(const half8*)(Ab + ((pi + 1) << 10) + slot);
#pragma unroll
            for (int jj = 0; jj < 4; ++jj)
                acc_hh[mt][jj] = __builtin_amdgcn_mfma_f32_16x16x32_f16(ah, bh[jj], acc_hh[mt][jj], 0, 0, 0);
#pragma unroll
            for (int jj = 0; jj < 4; ++jj)
                acc_c1[mt][jj] = __builtin_amdgcn_mfma_f32_16x16x32_f16(al, bh[jj], acc_c1[mt][jj], 0, 0, 0);
#pragma unroll
            for (int jj = 0; jj < 4; ++jj)
                acc_c1[mt][jj] = __builtin_amdgcn_mfma_f32_16x16x32_f16(ah, bl[jj], acc_c1[mt][jj], 0, 0, 0);
        }
    };

    // ---------------- main loop: 2 ksteps per iteration --------------------
    half8 bh0[4], bl0[4], bh1[4], bl1[4];

    stage_load(0);
    stage_write(0);
    __syncthreads();
    loadB(0, bh0, bl0);

    int cur = 0;
    for (int sp = 0; sp < KSTEPS; sp += 2) {
        const bool more = (sp + 2 < KSTEPS);
        if (more) stage_load(sp + 2);          // A global -> regs (hides under compute)
        loadB(sp + 1, bh1, bl1);
        computeK(cur, 0, bh0, bl0);
        if (more) loadB(sp + 2, bh0, bl0);
        computeK(cur, 1, bh1, bl1);
        if (more) stage_write(cur ^ 1);        // cvt + ds_write next chunk
        __syncthreads();
        cur ^= 1;
    }

    // ---------------- epilogue: logits -> LDS (overlays staging) -----------
#pragma unroll
    for (int mt = 0; mt < 4; ++mt)
#pragma unroll
        for (int jj = 0; jj < 4; ++jj)
#pragma unroll
            for (int r = 0; r < 4; ++r) {
                int row = mt * 16 + quad * 4 + r;
                int col = w * 64 + jj * 16 + lane15;
                L[row * 256 + col] =
                    (acc_hh[mt][jj][r] + acc_c1[mt][jj][r] * (1.0f / 4096.0f)) * (1.0f / 64.0f);
            }
    __syncthreads();

    // ---------------- gating: 4 lanes per token (verified R0 logic) --------
    const int t = tid >> 2;   // token 0..63
    const int p = tid & 3;    // experts [p*64, p*64+64), groups 2p, 2p+1
    float* Lrow = &L[t * 256];
    const int rot = 8 * p + t;

    // pass 1: sigmoid (stored back), biased score, per-group top-2
    float t0a = -1e30f, t1a = -1e30f, t0b = -1e30f, t1b = -1e30f;
    for (int i = 0; i < 64; ++i) {
        int col = p * 64 + ((i + rot) & 63);
        float x  = Lrow[col];
        float sg = 1.0f / (1.0f + expf(-x));
        Lrow[col] = sg;
        float swb = sg + bias[col];
        bool gb = (col >> 5) & 1;
        float c0 = gb ? t0b : t0a;
        float c1 = gb ? t1b : t1a;
        float n0 = fmaxf(c0, swb);
        float n1 = fmaxf(c1, fminf(c0, swb));
        if (gb) { t0b = n0; t1b = n1; } else { t0a = n0; t1a = n1; }
    }
    float gs0 = t0a + t1a;   // group 2p
    float gs1 = t0b + t1b;   // group 2p+1

    // collect other lanes' group scores (4-lane subgroup via xor 1,2)
    float o0 = __shfl_xor(gs0, 1), o1 = __shfl_xor(gs1, 1);
    float q0 = __shfl_xor(gs0, 2), q1 = __shfl_xor(gs1, 2);
    float r0 = __shfl_xor(o0, 2),  r1 = __shfl_xor(o1, 2);
    int g0 = 2 * p, g1 = 2 * p + 1;
    int go = 2 * (p ^ 1), gq = 2 * (p ^ 2), gr = 2 * (p ^ 3);
    auto beats = [](float v, int gv, float m, int gm) {
        return (v > m) || (v == m && gv < gm);
    };
    int rank0 = (int)beats(gs1, g1, gs0, g0)
              + (int)beats(o0, go, gs0, g0) + (int)beats(o1, go + 1, gs0, g0)
              + (int)beats(q0, gq, gs0, g0) + (int)beats(q1, gq + 1, gs0, g0)
              + (int)beats(r0, gr, gs0, g0) + (int)beats(r1, gr + 1, gs0, g0);
    int rank1 = (int)beats(gs0, g0, gs1, g1)
              + (int)beats(o0, go, gs1, g1) + (int)beats(o1, go + 1, gs1, g1)
              + (int)beats(q0, gq, gs1, g1) + (int)beats(q1, gq + 1, gs1, g1)
              + (int)beats(r0, gr, gs1, g1) + (int)beats(r1, gr + 1, gs1, g1);
    bool sel0 = rank0 < 4, sel1 = rank1 < 4;

    // pass 2: per-lane top-8 (value=swb, carry raw sigmoid + col)
    float lv[8], lsr[8]; int li[8];
#pragma unroll
    for (int k = 0; k < 8; ++k) { lv[k] = -1.0f; lsr[k] = 0.0f; li[k] = 1 << 30; }
    for (int i = 0; i < 64; ++i) {
        int col = p * 64 + ((i + rot) & 63);
        bool sel = ((col >> 5) & 1) ? sel1 : sel0;
        float sg  = Lrow[col];
        float swb = sg + bias[col];
        float v = (sel && swb > 0.0f) ? swb : -1.0f;
        if (v > lv[7]) {
            float cv = v, cs = sg; int ci = col;
#pragma unroll
            for (int k = 0; k < 8; ++k) {
                bool sw = cv > lv[k];
                float tv = lv[k], ts = lsr[k]; int ti = li[k];
                lv[k]  = sw ? cv : tv;  lsr[k] = sw ? cs : ts;  li[k] = sw ? ci : ti;
                cv = sw ? tv : cv;  cs = sw ? ts : cs;  ci = sw ? ti : ci;
            }
        }
    }

    // merge 4 lanes' lists: 8 rounds of butterfly-max, pop owner
    unsigned long long selmask = 0ull;
    float denom = 0.0f;
#pragma unroll
    for (int round = 0; round < 8; ++round) {
        float hv = lv[0], hs = lsr[0]; int hidx = li[0];
#pragma unroll
        for (int m = 1; m <= 2; m <<= 1) {
            float ov = __shfl_xor(hv, m);
            float os = __shfl_xor(hs, m);
            int   oi = __shfl_xor(hidx, m);
            bool take = (ov > hv) || (ov == hv && oi < hidx);
            hv = take ? ov : hv;  hs = take ? os : hs;  hidx = take ? oi : hidx;
        }
        if (hv > 0.0f) {
            denom += hs;
            if ((hidx >> 6) == p) selmask |= (1ull << (hidx & 63));
        }
        if (li[0] == hidx) {   // cols are unique across lanes -> unique owner
#pragma unroll
            for (int k = 0; k < 7; ++k) { lv[k] = lv[k + 1]; lsr[k] = lsr[k + 1]; li[k] = li[k + 1]; }
            lv[7] = -1.0f; lsr[7] = 0.0f; li[7] = 1 << 30;
        }
    }

    // pass 3: write output row (all 256 per token; zeros elsewhere)
    float inv = ROUTED_SCALE / (denom + 1e-20f);
    float* orow = out + (blockRow + (size_t)t) * NEXP;
    for (int i = 0; i < 64; i += 4) {
        int col = p * 64 + i;
        f32x4 v;
#pragma unroll
        for (int u = 0; u < 4; ++u) {
            float sg = Lrow[col + u];
            bool on = (selmask >> ((col + u) & 63)) & 1ull;
            v[u] = on ? sg * inv : 0.0f;
        }
        *(f32x4*)(orow + col) = v;
    }
}

extern "C" void kernel_launch(void* const* d_in, const int* in_sizes, int n_in,
                              void* d_out, int out_size, void* d_ws, size_t ws_size,
                              hipStream_t stream) {
    const float* hidden = (const float*)d_in[0];
    const float* weight = (const float*)d_in[1];
    const float* bias   = (const float*)d_in[2];
    float* out = (float*)d_out;
    _Float16* ws = (_Float16*)d_ws;   // needs 2*256*7168*2 = 7,340,032 bytes

    convert_w<<<NEXP, 256, 0, stream>>>(weight, ws);
    gate_kernel<<<16384 / BM, 256, 0, stream>>>(hidden, ws, bias, out);
}